// Round 2
// baseline (886.739 us; speedup 1.0000x reference)
//
#include <hip/hip_runtime.h>
#include <float.h>
#include <math.h>

#define Bdim 64
#define Qdim 32
#define Kdim 100
#define QK   (Qdim*Kdim)      // 3200
#define ROWLEN (Bdim*Kdim)    // 6400
#define EPT  (ROWLEN/256)     // 25

__device__ inline float wred_max(float v){ for(int o=32;o;o>>=1) v=fmaxf(v,__shfl_down(v,o)); return v; }
__device__ inline float wred_sum(float v){ for(int o=32;o;o>>=1) v+=__shfl_down(v,o); return v; }

// One block per (i, qq). Computes log_softmax over the (j,kk) row of 6400,
// writes atten, then the per-row tail: logit_m, conf, pseudo/top-k, loss
// accumulators, hard argmax index.
// NOTE: x_mask is a JAX bool array but the harness delivers integers as int32
// — reading it as bytes was the R1 bug (75% of lanes falsely masked).
__global__ __launch_bounds__(256) void conloss_main(
    const float* __restrict__ out_in, const float* __restrict__ conf_in,
    const int* __restrict__ bidx, const int* __restrict__ xmask,
    const int* __restrict__ topk_p,
    float* __restrict__ atten_o, float* __restrict__ logitm_o,
    float* __restrict__ pseudo_o, float* __restrict__ conf_o,
    float* __restrict__ acc, int* __restrict__ hard_o)
{
    const int blk = blockIdx.x;
    const int i   = blk >> 5;          // / Qdim
    const int qq  = blk & 31;          // % Qdim
    const int tid = threadIdx.x;
    const size_t base = (size_t)i*(Bdim*QK) + (size_t)qq*Kdim;

    // pass 1: load row into registers, compute max
    float vals[EPT];
    float lmax = -INFINITY;
    #pragma unroll
    for (int c = 0; c < EPT; ++c) {
        int e = tid + c*256;
        int j = e / Kdim, kk = e - j*Kdim;
        float v = out_in[base + (size_t)j*QK + kk] * (1.0f/0.07f);
        vals[c] = v;
        lmax = fmaxf(lmax, v);
    }
    __shared__ float red[4];
    __shared__ float s_max, s_lse;
    const int wid = tid >> 6, lane = tid & 63;
    float wm = wred_max(lmax);
    if (lane == 0) red[wid] = wm;
    __syncthreads();
    if (tid == 0) s_max = fmaxf(fmaxf(red[0],red[1]), fmaxf(red[2],red[3]));
    __syncthreads();
    const float m = s_max;
    float ls = 0.f;
    #pragma unroll
    for (int c = 0; c < EPT; ++c) ls += expf(vals[c] - m);
    float wsum = wred_sum(ls);
    if (lane == 0) red[wid] = wsum;
    __syncthreads();
    if (tid == 0) s_lse = m + logf(red[0]+red[1]+red[2]+red[3]);
    __syncthreads();
    const float lse = s_lse;

    // pass 2: write atten, capture diagonal logit into LDS
    __shared__ float sm_logit[Kdim];
    #pragma unroll
    for (int c = 0; c < EPT; ++c) {
        int e = tid + c*256;
        int j = e / Kdim, kk = e - j*Kdim;
        float a = vals[c] - lse;
        atten_o[base + (size_t)j*QK + kk] = a;
        if (j == i) sm_logit[kk] = a;
    }
    __syncthreads();

    // per-(i,qq) tail over Kdim=100
    __shared__ float sm_pseudo[Kdim], sm_lm[Kdim];
    __shared__ float s_cm, s_cs;
    __shared__ unsigned long long s_sel[2];
    const size_t ro = (size_t)i*QK + (size_t)qq*Kdim;
    const int row = bidx[i];
    if (tid < Kdim) {
        int kk = tid;
        bool xm = xmask[ro + kk] != 0;
        float pr = xm ? conf_in[(size_t)row*QK + (size_t)qq*Kdim + kk] : 0.0f;
        sm_pseudo[kk] = pr;
        float lm = xm ? sm_logit[kk] : -FLT_MAX;
        sm_lm[kk] = lm;
        logitm_o[ro + kk] = lm;
    }
    __syncthreads();
    if (tid == 0) {
        // conf softmax stats
        float cm = -FLT_MAX;
        for (int kk = 0; kk < Kdim; ++kk) cm = fmaxf(cm, sm_lm[kk]);
        float cs = 0.f;
        for (int kk = 0; kk < Kdim; ++kk) cs += expf(sm_lm[kk] - cm);
        s_cm = cm; s_cs = cs;
        // top-k on pseudo (values desc, ties -> lower index, matches lax.top_k)
        int kt = *topk_p; if (kt > Kdim) kt = Kdim;
        unsigned long long sel0 = 0ull, sel1 = 0ull;
        for (int t = 0; t < kt; ++t) {
            float bv = -INFINITY; int bsel = -1;
            for (int kk = 0; kk < Kdim; ++kk) {
                bool taken = (kk < 64) ? ((sel0 >> kk) & 1ull) : ((sel1 >> (kk-64)) & 1ull);
                if (!taken && sm_pseudo[kk] > bv) { bv = sm_pseudo[kk]; bsel = kk; }
            }
            if (bsel >= 0) { if (bsel < 64) sel0 |= 1ull<<bsel; else sel1 |= 1ull<<(bsel-64); }
        }
        s_sel[0] = sel0; s_sel[1] = sel1;
        // loss numerator: sum over selected of pseudo*logit (pseudo already 0 where masked off)
        float lsum = 0.f;
        for (int kk = 0; kk < Kdim; ++kk) {
            bool selb = (kk<64) ? ((sel0>>kk)&1ull) : ((sel1>>(kk-64))&1ull);
            if (selb) lsum += sm_pseudo[kk] * sm_logit[kk];
        }
        atomicAdd(&acc[0], lsum);
        bool phrase = ((sel0 & 1ull) != 0) && (xmask[ro] != 0);
        if (phrase) atomicAdd(&acc[1], 1.0f);
        // hard = argmax of masked conf (first occurrence of max)
        float bv = -1.f; int barg = 0;
        for (int kk = 0; kk < Kdim; ++kk) {
            bool xm = xmask[ro+kk] != 0;
            float cv = xm ? expf(sm_lm[kk]-cm)/cs : 0.f;
            if (cv > bv) { bv = cv; barg = kk; }
        }
        hard_o[i*Qdim + qq] = barg;
    }
    __syncthreads();
    if (tid < Kdim) {
        int kk = tid;
        bool xm = xmask[ro+kk] != 0;
        float cv = xm ? expf(sm_lm[kk]-s_cm)/s_cs : 0.f;
        conf_o[ro+kk] = cv;
        bool selb = (kk<64) ? ((s_sel[0]>>kk)&1ull) : ((s_sel[1]>>(kk-64))&1ull);
        pseudo_o[ro+kk] = selb ? sm_pseudo[kk] : 0.f;
    }
}

// Plain grid-stride dword copy (dst is 4B-aligned only: output slab starts at
// float offset 13,721,601). Unrolled x4 to keep 4 loads in flight per wave.
__global__ __launch_bounds__(256) void conloss_copy(
    const float* __restrict__ src, float* __restrict__ dst, long long n)
{
    long long idx = (long long)blockIdx.x*blockDim.x + threadIdx.x;
    const long long stride = (long long)gridDim.x*blockDim.x;
    for (; idx + 3*stride < n; idx += 4*stride) {
        float a = src[idx];
        float b = src[idx +   stride];
        float c = src[idx + 2*stride];
        float d = src[idx + 3*stride];
        dst[idx]            = a;
        dst[idx +   stride] = b;
        dst[idx + 2*stride] = c;
        dst[idx + 3*stride] = d;
    }
    for (; idx < n; idx += stride) dst[idx] = src[idx];
}

// EMA overwrite of the 64 gathered rows; last-write-wins for duplicate indices.
__global__ __launch_bounds__(256) void conloss_ema(
    const float* __restrict__ conf_in, const int* __restrict__ bidx,
    const int* __restrict__ xmask, const int* __restrict__ hard,
    float* __restrict__ newconf_o)
{
    const int i = blockIdx.x;
    const int row = bidx[i];
    for (int ii = i+1; ii < Bdim; ++ii) if (bidx[ii] == row) return; // later write wins
    for (int e = threadIdx.x; e < QK; e += blockDim.x) {
        int qq = e / Kdim, kk = e - qq*Kdim;
        bool xm = xmask[(size_t)i*QK + e] != 0;
        float h = (xm && kk == hard[i*Qdim + qq]) ? 1.0f : 0.0f;
        newconf_o[(size_t)row*QK + e] = 0.99f*conf_in[(size_t)row*QK + e] + 0.01f*h;
    }
}

__global__ void conloss_final(const float* __restrict__ acc, float* __restrict__ loss_o)
{
    // loss = -(sum pseudo*logit) / (phrase_count + float32 eps), * BASE_TEMPERATURE(1.0)
    loss_o[0] = -acc[0] / (acc[1] + 1.1920929e-07f);
}

extern "C" void kernel_launch(void* const* d_in, const int* in_sizes, int n_in,
                              void* d_out, int out_size, void* d_ws, size_t ws_size,
                              hipStream_t stream) {
    const float* out_in  = (const float*)d_in[0];
    const float* conf_in = (const float*)d_in[1];
    const int*   bidx    = (const int*)d_in[2];
    const int*   xmask   = (const int*)d_in[3];
    const int*   topk    = (const int*)d_in[4];

    float* o = (float*)d_out;
    float* loss_o   = o;
    float* atten_o  = o + 1;
    float* logitm_o = atten_o + (size_t)Bdim*Bdim*Qdim*Kdim;   // +13,107,200
    float* pseudo_o = logitm_o + (size_t)Bdim*Qdim*Kdim;       // +204,800
    float* conf_o   = pseudo_o + (size_t)Bdim*Qdim*Kdim;
    float* newconf_o= conf_o   + (size_t)Bdim*Qdim*Kdim;

    float* acc  = (float*)d_ws;
    int*   hard = (int*)((char*)d_ws + 64);

    const long long nconf = (long long)in_sizes[1];            // 96,000,000

    hipMemsetAsync(d_ws, 0, 64, stream);
    conloss_main<<<Bdim*Qdim, 256, 0, stream>>>(out_in, conf_in, bidx, xmask, topk,
                                                atten_o, logitm_o, pseudo_o, conf_o,
                                                acc, hard);
    conloss_copy<<<16384, 256, 0, stream>>>(conf_in, newconf_o, nconf);
    conloss_ema<<<Bdim, 256, 0, stream>>>(conf_in, bidx, xmask, hard, newconf_o);
    conloss_final<<<1, 1, 0, stream>>>(acc, loss_o);
}